// Round 1
// baseline (683.795 us; speedup 1.0000x reference)
//
#include <hip/hip_runtime.h>
#include <hip/hip_bf16.h>
#include <cstdint>

// ---------------- CSR build ----------------

__global__ __launch_bounds__(256) void count_k(const int* __restrict__ ei,
                                               int* __restrict__ cnt, int E) {
    int e = blockIdx.x * 256 + threadIdx.x;
    if (e < E) atomicAdd(&cnt[ei[(size_t)E + e]], 1);   // dst row
}

__global__ __launch_bounds__(256) void dinv_k(const int* __restrict__ cnt,
                                              float* __restrict__ dinv, int n) {
    int i = blockIdx.x * 256 + threadIdx.x;
    if (i < n) dinv[i] = rsqrtf((float)(cnt[i] + 1));   // +1 self-loop; deg>=1 always
}

// exclusive scan, 1024 elems per block (256 thr x 4)
__global__ __launch_bounds__(256) void scan1_k(const int* __restrict__ cnt,
                                               int* __restrict__ rp,
                                               int* __restrict__ bsum, int n) {
    __shared__ int s[256];
    int t = threadIdx.x;
    int base = blockIdx.x * 1024 + t * 4;
    int c[4];
#pragma unroll
    for (int j = 0; j < 4; ++j) c[j] = (base + j < n) ? cnt[base + j] : 0;
    int tl = c[0] + c[1] + c[2] + c[3];
    s[t] = tl;
    __syncthreads();
    for (int off = 1; off < 256; off <<= 1) {
        int v = (t >= off) ? s[t - off] : 0;
        __syncthreads();
        s[t] += v;
        __syncthreads();
    }
    int run = s[t] - tl;   // exclusive across threads within block
#pragma unroll
    for (int j = 0; j < 4; ++j) {
        if (base + j < n) rp[base + j] = run;
        run += c[j];
    }
    if (t == 255) bsum[blockIdx.x] = s[255];
}

__global__ __launch_bounds__(256) void scan2_k(const int* __restrict__ bsum,
                                               int* __restrict__ boff, int nb) {
    __shared__ int s[256];
    int t = threadIdx.x;
    int v0 = (t < nb) ? bsum[t] : 0;
    s[t] = v0;
    __syncthreads();
    for (int off = 1; off < 256; off <<= 1) {
        int v = (t >= off) ? s[t - off] : 0;
        __syncthreads();
        s[t] += v;
        __syncthreads();
    }
    if (t < nb) boff[t] = s[t] - v0;   // exclusive block offsets
}

__global__ __launch_bounds__(256) void scan3_k(int* __restrict__ rp,
                                               int* __restrict__ cursor,
                                               const int* __restrict__ boff,
                                               int n, int etot) {
    int i = blockIdx.x * 256 + threadIdx.x;
    if (i < n) {
        int v = rp[i] + boff[i >> 10];
        rp[i] = v;
        cursor[i] = v;
    }
    if (i == 0) rp[n] = etot;
}

__global__ __launch_bounds__(256) void fill_k(const int* __restrict__ ei,
                                              int* __restrict__ cursor,
                                              int* __restrict__ eb, int E) {
    int e = blockIdx.x * 256 + threadIdx.x;
    if (e < E) {
        int d = ei[(size_t)E + e];
        int p = atomicAdd(&cursor[d], 1);
        eb[p] = ei[e];   // src
    }
}

// ---------------- GEMM: out[r][c] = (sum_k X[r][k]*W[k][c]) * dinv[r] ----------------
// K fixed = 128. Block 256 threads. Per thread: TR rows x 16 cols.

template <int OUTC, int TR>
__global__ __launch_bounds__(256) void gemm_k(const float* __restrict__ X,
                                              const float* __restrict__ W,
                                              const float* __restrict__ dinv,
                                              float* __restrict__ out, int n) {
    constexpr int CT = OUTC / 16;       // col-thread groups
    constexpr int RT = 256 / CT;        // row threads
    constexpr int ROWS = RT * TR;       // rows per block
    constexpr int XP = 132;             // padded row stride (bank-conflict: 2-way only)
    __shared__ float Ws[128 * OUTC];
    __shared__ float xs[ROWS * XP];

    int t = threadIdx.x;
    int r0b = blockIdx.x * ROWS;

    // stage W (once per block)
    for (int i = t; i < 128 * OUTC / 4; i += 256)
        ((float4*)Ws)[i] = ((const float4*)W)[i];
    // stage X tile, padded stride
    for (int i = t; i < ROWS * 32; i += 256) {
        int r = i >> 5, kq = i & 31;
        float4 v = make_float4(0.f, 0.f, 0.f, 0.f);
        if (r0b + r < n) v = ((const float4*)X)[(size_t)(r0b + r) * 32 + kq];
        *(float4*)&xs[r * XP + kq * 4] = v;
    }
    __syncthreads();

    int rt = t / CT, cg = t % CT;
    int r0 = rt * TR, c0 = cg * 16;
    float acc[TR][16];
#pragma unroll
    for (int a = 0; a < TR; ++a)
#pragma unroll
        for (int j = 0; j < 16; ++j) acc[a][j] = 0.f;

#pragma unroll 4
    for (int k = 0; k < 128; ++k) {
        float4 wa = *(const float4*)&Ws[k * OUTC + c0];
        float4 wb = *(const float4*)&Ws[k * OUTC + c0 + 4];
        float4 wc = *(const float4*)&Ws[k * OUTC + c0 + 8];
        float4 wd = *(const float4*)&Ws[k * OUTC + c0 + 12];
#pragma unroll
        for (int a = 0; a < TR; ++a) {
            float xv = xs[(r0 + a) * XP + k];
            acc[a][0] += xv * wa.x;  acc[a][1] += xv * wa.y;
            acc[a][2] += xv * wa.z;  acc[a][3] += xv * wa.w;
            acc[a][4] += xv * wb.x;  acc[a][5] += xv * wb.y;
            acc[a][6] += xv * wb.z;  acc[a][7] += xv * wb.w;
            acc[a][8] += xv * wc.x;  acc[a][9] += xv * wc.y;
            acc[a][10] += xv * wc.z; acc[a][11] += xv * wc.w;
            acc[a][12] += xv * wd.x; acc[a][13] += xv * wd.y;
            acc[a][14] += xv * wd.z; acc[a][15] += xv * wd.w;
        }
    }

#pragma unroll
    for (int a = 0; a < TR; ++a) {
        int r = r0b + r0 + a;
        if (r < n) {
            float di = dinv[r];
            float* op = &out[(size_t)r * OUTC + c0];
#pragma unroll
            for (int q = 0; q < 4; ++q) {
                float4 v = make_float4(acc[a][4 * q] * di, acc[a][4 * q + 1] * di,
                                       acc[a][4 * q + 2] * di, acc[a][4 * q + 3] * di);
                *(float4*)&op[4 * q] = v;
            }
        }
    }
}

// ---------------- Aggregation: out[i] = (hs[i] + sum_{src in N(i)} hs[src]) * dinv[i] + b ----------------
// hs rows are pre-scaled by dinv[row]. One wave per node.

template <int C, bool RELU>
__global__ __launch_bounds__(256) void agg_k(const float* __restrict__ hs,
                                             const int* __restrict__ rp,
                                             const int* __restrict__ eb,
                                             const float* __restrict__ dinv,
                                             const float* __restrict__ bias,
                                             float* __restrict__ out, int n) {
    int wid = (blockIdx.x * 256 + threadIdx.x) >> 6;
    int lane = threadIdx.x & 63;
    if (wid >= n) return;
    int e0 = rp[wid], e1 = rp[wid + 1];
    float di = dinv[wid];

    if constexpr (C == 128) {
        size_t so = (size_t)wid * 128 + lane * 2;
        float2 acc = *(const float2*)&hs[so];
        for (int e = e0; e < e1; ++e) {
            int s = eb[e];
            float2 v = *(const float2*)&hs[(size_t)s * 128 + lane * 2];
            acc.x += v.x;
            acc.y += v.y;
        }
        float2 b = *(const float2*)&bias[lane * 2];
        float ox = acc.x * di + b.x;
        float oy = acc.y * di + b.y;
        if (RELU) {
            ox = fmaxf(ox, 0.f);
            oy = fmaxf(oy, 0.f);
        }
        *(float2*)&out[so] = make_float2(ox, oy);
    } else {
        size_t so = (size_t)wid * C + lane;
        float acc = hs[so];
        for (int e = e0; e < e1; ++e) {
            int s = eb[e];
            acc += hs[(size_t)s * C + lane];
        }
        float o = acc * di + bias[lane];
        if (RELU) o = fmaxf(o, 0.f);
        out[so] = o;
    }
}

// ---------------- launch ----------------

extern "C" void kernel_launch(void* const* d_in, const int* in_sizes, int n_in,
                              void* d_out, int out_size, void* d_ws, size_t ws_size,
                              hipStream_t stream) {
    const float* x  = (const float*)d_in[0];
    const int*   ei = (const int*)d_in[1];
    const float* W1 = (const float*)d_in[2];
    const float* b1 = (const float*)d_in[3];
    const float* W2 = (const float*)d_in[4];
    const float* b2 = (const float*)d_in[5];
    float* out = (float*)d_out;

    int n = in_sizes[0] / 128;
    int E = in_sizes[1] / 2;

    char* ws = (char*)d_ws;
    size_t o = 0;
    auto alloc = [&](size_t bytes) {
        size_t r = o;
        o = (o + bytes + 255) & ~(size_t)255;
        return r;
    };
    int*   cnt    = (int*)(ws + alloc((size_t)n * 4));
    float* dinv   = (float*)(ws + alloc((size_t)n * 4));
    int*   rp     = (int*)(ws + alloc((size_t)(n + 1) * 4));
    int*   cursor = (int*)(ws + alloc((size_t)n * 4));
    int*   boff   = (int*)(ws + alloc(256 * 4));
    int*   bsum   = (int*)(ws + alloc(256 * 4));
    int*   eb     = (int*)(ws + alloc((size_t)E * 4));
    float* bufA   = (float*)(ws + alloc((size_t)n * 128 * 4));  // h1s, then h2s
    float* bufB   = (float*)(ws + alloc((size_t)n * 128 * 4));  // a1

    int gE = (E + 255) / 256;
    int gN = (n + 255) / 256;
    int nb = (n + 1023) / 1024;
    int gW = (int)(((size_t)n * 64 + 255) / 256);   // wave-per-node grids

    hipMemsetAsync(cnt, 0, (size_t)n * 4, stream);
    count_k<<<gE, 256, 0, stream>>>(ei, cnt, E);
    dinv_k<<<gN, 256, 0, stream>>>(cnt, dinv, n);
    scan1_k<<<nb, 256, 0, stream>>>(cnt, rp, bsum, n);
    scan2_k<<<1, 256, 0, stream>>>(bsum, boff, nb);
    scan3_k<<<gN, 256, 0, stream>>>(rp, cursor, boff, n, E);
    fill_k<<<gE, 256, 0, stream>>>(ei, cursor, eb, E);

    // layer 1: h1s = (x@W1) * dinv ; a1 = relu(agg(h1s)*dinv + b1)
    gemm_k<128, 4><<<(n + 127) / 128, 256, 0, stream>>>(x, W1, dinv, bufA, n);
    agg_k<128, true><<<gW, 256, 0, stream>>>(bufA, rp, eb, dinv, b1, bufB, n);
    // layer 2: h2s = (a1@W2) * dinv ; out = agg(h2s)*dinv + b2
    gemm_k<64, 2><<<(n + 127) / 128, 256, 0, stream>>>(bufB, W2, dinv, bufA, n);
    agg_k<64, false><<<gW, 256, 0, stream>>>(bufA, rp, eb, dinv, b2, out, n);
}

// Round 2
// 497.437 us; speedup vs baseline: 1.3746x; 1.3746x over previous
//
#include <hip/hip_runtime.h>
#include <hip/hip_bf16.h>
#include <cstdint>

// ---------------- bf16 helpers ----------------

__device__ inline float blo(uint u) { return __uint_as_float(u << 16); }
__device__ inline float bhi(uint u) { return __uint_as_float(u & 0xffff0000u); }
__device__ inline ushort f2bu(float x) {
    __hip_bfloat16 h = __float2bfloat16(x);
    return *reinterpret_cast<ushort*>(&h);
}
__device__ inline uint fpack2(float x, float y) {
    return (uint)f2bu(x) | ((uint)f2bu(y) << 16);
}

// ---------------- CSR build ----------------

__global__ __launch_bounds__(256) void count_k(const int* __restrict__ ei,
                                               int* __restrict__ cnt, int E) {
    int e = blockIdx.x * 256 + threadIdx.x;
    if (e < E) atomicAdd(&cnt[ei[(size_t)E + e]], 1);   // dst row
}

__global__ __launch_bounds__(256) void dinv_k(const int* __restrict__ cnt,
                                              float* __restrict__ dinv, int n) {
    int i = blockIdx.x * 256 + threadIdx.x;
    if (i < n) dinv[i] = rsqrtf((float)(cnt[i] + 1));   // +1 self-loop
}

__global__ __launch_bounds__(256) void scan1_k(const int* __restrict__ cnt,
                                               int* __restrict__ rp,
                                               int* __restrict__ bsum, int n) {
    __shared__ int s[256];
    int t = threadIdx.x;
    int base = blockIdx.x * 1024 + t * 4;
    int c[4];
#pragma unroll
    for (int j = 0; j < 4; ++j) c[j] = (base + j < n) ? cnt[base + j] : 0;
    int tl = c[0] + c[1] + c[2] + c[3];
    s[t] = tl;
    __syncthreads();
    for (int off = 1; off < 256; off <<= 1) {
        int v = (t >= off) ? s[t - off] : 0;
        __syncthreads();
        s[t] += v;
        __syncthreads();
    }
    int run = s[t] - tl;
#pragma unroll
    for (int j = 0; j < 4; ++j) {
        if (base + j < n) rp[base + j] = run;
        run += c[j];
    }
    if (t == 255) bsum[blockIdx.x] = s[255];
}

__global__ __launch_bounds__(256) void scan2_k(const int* __restrict__ bsum,
                                               int* __restrict__ boff, int nb) {
    __shared__ int s[256];
    int t = threadIdx.x;
    int v0 = (t < nb) ? bsum[t] : 0;
    s[t] = v0;
    __syncthreads();
    for (int off = 1; off < 256; off <<= 1) {
        int v = (t >= off) ? s[t - off] : 0;
        __syncthreads();
        s[t] += v;
        __syncthreads();
    }
    if (t < nb) boff[t] = s[t] - v0;
}

__global__ __launch_bounds__(256) void scan3_k(int* __restrict__ rp,
                                               int* __restrict__ cursor,
                                               const int* __restrict__ boff,
                                               int n, int etot) {
    int i = blockIdx.x * 256 + threadIdx.x;
    if (i < n) {
        int v = rp[i] + boff[i >> 10];
        rp[i] = v;
        cursor[i] = v;
    }
    if (i == 0) rp[n] = etot;
}

__global__ __launch_bounds__(256) void fill_k(const int* __restrict__ ei,
                                              int* __restrict__ cursor,
                                              int* __restrict__ eb, int E) {
    int e = blockIdx.x * 256 + threadIdx.x;
    if (e < E) {
        int d = ei[(size_t)E + e];
        int p = atomicAdd(&cursor[d], 1);
        eb[p] = ei[e];   // src
    }
}

// ---------------- GEMM: out[r][c] = (sum_k X[r][k]*W[k][c]) * dinv[r] ----------------
// K fixed = 128. INB: X is bf16-packed (uint2 = 4ch). OUT always bf16-packed.

template <int OUTC, int TR, bool INB>
__global__ __launch_bounds__(256) void gemm_k(const void* __restrict__ Xv,
                                              const float* __restrict__ W,
                                              const float* __restrict__ dinv,
                                              uint* __restrict__ outb, int n) {
    constexpr int CT = OUTC / 16;
    constexpr int RT = 256 / CT;
    constexpr int ROWS = RT * TR;
    constexpr int XP = 132;
    __shared__ float Ws[128 * OUTC];
    __shared__ float xs[ROWS * XP];

    int t = threadIdx.x;
    int r0b = blockIdx.x * ROWS;

    for (int i = t; i < 128 * OUTC / 4; i += 256)
        ((float4*)Ws)[i] = ((const float4*)W)[i];

    for (int i = t; i < ROWS * 32; i += 256) {
        int r = i >> 5, kq = i & 31;
        float4 v = make_float4(0.f, 0.f, 0.f, 0.f);
        if (r0b + r < n) {
            if constexpr (INB) {
                uint2 u = ((const uint2*)Xv)[(size_t)(r0b + r) * 32 + kq];
                v = make_float4(blo(u.x), bhi(u.x), blo(u.y), bhi(u.y));
            } else {
                v = ((const float4*)Xv)[(size_t)(r0b + r) * 32 + kq];
            }
        }
        *(float4*)&xs[r * XP + kq * 4] = v;
    }
    __syncthreads();

    int rt = t / CT, cg = t % CT;
    int r0 = rt * TR, c0 = cg * 16;
    float acc[TR][16];
#pragma unroll
    for (int a = 0; a < TR; ++a)
#pragma unroll
        for (int j = 0; j < 16; ++j) acc[a][j] = 0.f;

#pragma unroll 4
    for (int k = 0; k < 128; ++k) {
        float4 wa = *(const float4*)&Ws[k * OUTC + c0];
        float4 wb = *(const float4*)&Ws[k * OUTC + c0 + 4];
        float4 wc = *(const float4*)&Ws[k * OUTC + c0 + 8];
        float4 wd = *(const float4*)&Ws[k * OUTC + c0 + 12];
#pragma unroll
        for (int a = 0; a < TR; ++a) {
            float xv = xs[(r0 + a) * XP + k];
            acc[a][0] += xv * wa.x;  acc[a][1] += xv * wa.y;
            acc[a][2] += xv * wa.z;  acc[a][3] += xv * wa.w;
            acc[a][4] += xv * wb.x;  acc[a][5] += xv * wb.y;
            acc[a][6] += xv * wb.z;  acc[a][7] += xv * wb.w;
            acc[a][8] += xv * wc.x;  acc[a][9] += xv * wc.y;
            acc[a][10] += xv * wc.z; acc[a][11] += xv * wc.w;
            acc[a][12] += xv * wd.x; acc[a][13] += xv * wd.y;
            acc[a][14] += xv * wd.z; acc[a][15] += xv * wd.w;
        }
    }

#pragma unroll
    for (int a = 0; a < TR; ++a) {
        int r = r0b + r0 + a;
        if (r < n) {
            float di = dinv[r];
            uint* op = &outb[(size_t)r * (OUTC / 2) + c0 / 2];
#pragma unroll
            for (int q = 0; q < 2; ++q) {
                uint2 v = make_uint2(
                    fpack2(acc[a][8 * q + 0] * di, acc[a][8 * q + 1] * di),
                    fpack2(acc[a][8 * q + 2] * di, acc[a][8 * q + 3] * di));
                uint2 w = make_uint2(
                    fpack2(acc[a][8 * q + 4] * di, acc[a][8 * q + 5] * di),
                    fpack2(acc[a][8 * q + 6] * di, acc[a][8 * q + 7] * di));
                *(uint2*)&op[4 * q] = v;
                *(uint2*)&op[4 * q + 2] = w;
            }
        }
    }
}

// ---------------- Aggregation, 128 ch bf16 in / bf16 out, ReLU ----------------
// hs rows pre-scaled by dinv[row]. One wave per node; lane covers ch pair 2l,2l+1.

__global__ __launch_bounds__(256) void agg128_k(const uint* __restrict__ hs,
                                                const int* __restrict__ rp,
                                                const int* __restrict__ eb,
                                                const float* __restrict__ dinv,
                                                const float* __restrict__ bias,
                                                uint* __restrict__ outb, int n) {
    int wid = (blockIdx.x * 256 + threadIdx.x) >> 6;
    int lane = threadIdx.x & 63;
    if (wid >= n) return;
    int e0 = rp[wid], e1 = rp[wid + 1];
    float di = dinv[wid];
    const uint* base = hs + lane;

    uint self = base[(size_t)wid << 6];
    float ax = blo(self), ay = bhi(self);

    int e = e0;
    for (; e + 8 <= e1; e += 8) {
        int s0 = eb[e + 0], s1 = eb[e + 1], s2 = eb[e + 2], s3 = eb[e + 3];
        int s4 = eb[e + 4], s5 = eb[e + 5], s6 = eb[e + 6], s7 = eb[e + 7];
        uint v0 = base[(size_t)s0 << 6];
        uint v1 = base[(size_t)s1 << 6];
        uint v2 = base[(size_t)s2 << 6];
        uint v3 = base[(size_t)s3 << 6];
        uint v4 = base[(size_t)s4 << 6];
        uint v5 = base[(size_t)s5 << 6];
        uint v6 = base[(size_t)s6 << 6];
        uint v7 = base[(size_t)s7 << 6];
        ax += ((blo(v0) + blo(v1)) + (blo(v2) + blo(v3))) +
              ((blo(v4) + blo(v5)) + (blo(v6) + blo(v7)));
        ay += ((bhi(v0) + bhi(v1)) + (bhi(v2) + bhi(v3))) +
              ((bhi(v4) + bhi(v5)) + (bhi(v6) + bhi(v7)));
    }
    for (; e < e1; ++e) {
        uint v = base[(size_t)eb[e] << 6];
        ax += blo(v);
        ay += bhi(v);
    }

    float ox = fmaxf(ax * di + bias[lane * 2], 0.f);
    float oy = fmaxf(ay * di + bias[lane * 2 + 1], 0.f);
    outb[((size_t)wid << 6) + lane] = fpack2(ox, oy);
}

// ---------------- Aggregation, 64 ch bf16 in / f32 out, 2 nodes per wave ----------------

__global__ __launch_bounds__(256) void agg64_k(const uint* __restrict__ hs,
                                               const int* __restrict__ rp,
                                               const int* __restrict__ eb,
                                               const float* __restrict__ dinv,
                                               const float* __restrict__ bias,
                                               float* __restrict__ out, int n) {
    int gw = (blockIdx.x * 256 + threadIdx.x) >> 6;
    int lane = threadIdx.x & 63;
    int node = gw * 2 + (lane >> 5);
    int cl = lane & 31;
    if (node >= n) return;
    int e0 = rp[node], e1 = rp[node + 1];
    float di = dinv[node];
    const uint* base = hs + cl;

    uint self = base[(size_t)node << 5];
    float ax = blo(self), ay = bhi(self);

    int e = e0;
    for (; e + 8 <= e1; e += 8) {
        int s0 = eb[e + 0], s1 = eb[e + 1], s2 = eb[e + 2], s3 = eb[e + 3];
        int s4 = eb[e + 4], s5 = eb[e + 5], s6 = eb[e + 6], s7 = eb[e + 7];
        uint v0 = base[(size_t)s0 << 5];
        uint v1 = base[(size_t)s1 << 5];
        uint v2 = base[(size_t)s2 << 5];
        uint v3 = base[(size_t)s3 << 5];
        uint v4 = base[(size_t)s4 << 5];
        uint v5 = base[(size_t)s5 << 5];
        uint v6 = base[(size_t)s6 << 5];
        uint v7 = base[(size_t)s7 << 5];
        ax += ((blo(v0) + blo(v1)) + (blo(v2) + blo(v3))) +
              ((blo(v4) + blo(v5)) + (blo(v6) + blo(v7)));
        ay += ((bhi(v0) + bhi(v1)) + (bhi(v2) + bhi(v3))) +
              ((bhi(v4) + bhi(v5)) + (bhi(v6) + bhi(v7)));
    }
    for (; e < e1; ++e) {
        uint v = base[(size_t)eb[e] << 5];
        ax += blo(v);
        ay += bhi(v);
    }

    float ox = ax * di + bias[cl * 2];
    float oy = ay * di + bias[cl * 2 + 1];
    *(float2*)&out[((size_t)node << 6) + cl * 2] = make_float2(ox, oy);
}

// ---------------- launch ----------------

extern "C" void kernel_launch(void* const* d_in, const int* in_sizes, int n_in,
                              void* d_out, int out_size, void* d_ws, size_t ws_size,
                              hipStream_t stream) {
    const float* x  = (const float*)d_in[0];
    const int*   ei = (const int*)d_in[1];
    const float* W1 = (const float*)d_in[2];
    const float* b1 = (const float*)d_in[3];
    const float* W2 = (const float*)d_in[4];
    const float* b2 = (const float*)d_in[5];
    float* out = (float*)d_out;

    int n = in_sizes[0] / 128;
    int E = in_sizes[1] / 2;

    char* ws = (char*)d_ws;
    size_t o = 0;
    auto alloc = [&](size_t bytes) {
        size_t r = o;
        o = (o + bytes + 255) & ~(size_t)255;
        return r;
    };
    int*   cnt    = (int*)(ws + alloc((size_t)n * 4));
    float* dinv   = (float*)(ws + alloc((size_t)n * 4));
    int*   rp     = (int*)(ws + alloc((size_t)(n + 1) * 4));
    int*   cursor = (int*)(ws + alloc((size_t)n * 4));
    int*   boff   = (int*)(ws + alloc(256 * 4));
    int*   bsum   = (int*)(ws + alloc(256 * 4));
    int*   eb     = (int*)(ws + alloc((size_t)E * 4));
    uint*  h1s    = (uint*)(ws + alloc((size_t)n * 64 * 4));  // bf16 x2, 128 ch
    uint*  a1     = (uint*)(ws + alloc((size_t)n * 64 * 4));  // bf16 x2, 128 ch
    uint*  h2s    = (uint*)(ws + alloc((size_t)n * 32 * 4));  // bf16 x2, 64 ch

    int gE = (E + 255) / 256;
    int gN = (n + 255) / 256;
    int nb = (n + 1023) / 1024;
    int gW1 = (int)(((size_t)n * 64 + 255) / 256);              // 1 wave/node
    int nw2 = (n + 1) / 2;
    int gW2 = (int)(((size_t)nw2 * 64 + 255) / 256);            // 2 nodes/wave

    hipMemsetAsync(cnt, 0, (size_t)n * 4, stream);
    count_k<<<gE, 256, 0, stream>>>(ei, cnt, E);
    dinv_k<<<gN, 256, 0, stream>>>(cnt, dinv, n);
    scan1_k<<<nb, 256, 0, stream>>>(cnt, rp, bsum, n);
    scan2_k<<<1, 256, 0, stream>>>(bsum, boff, nb);
    scan3_k<<<gN, 256, 0, stream>>>(rp, cursor, boff, n, E);
    fill_k<<<gE, 256, 0, stream>>>(ei, cursor, eb, E);

    // layer 1: h1s = bf16((x@W1) * dinv) ; a1 = bf16(relu(agg(h1s)*dinv + b1))
    gemm_k<128, 4, false><<<(n + 127) / 128, 256, 0, stream>>>(x, W1, dinv, h1s, n);
    agg128_k<<<gW1, 256, 0, stream>>>(h1s, rp, eb, dinv, b1, a1, n);
    // layer 2: h2s = bf16((a1@W2) * dinv) ; out = agg(h2s)*dinv + b2  (f32)
    gemm_k<64, 2, true><<<(n + 127) / 128, 256, 0, stream>>>(a1, W2, dinv, h2s, n);
    agg64_k<<<gW2, 256, 0, stream>>>(h2s, rp, eb, dinv, b2, out, n);
}

// Round 4
// 229.108 us; speedup vs baseline: 2.9846x; 2.1712x over previous
//
#include <hip/hip_runtime.h>
#include <hip/hip_bf16.h>
#include <cstdint>

typedef short bf16x8 __attribute__((ext_vector_type(8)));
typedef float f32x4 __attribute__((ext_vector_type(4)));

// ---------------- bf16 helpers ----------------

__device__ inline float blo(uint u) { return __uint_as_float(u << 16); }
__device__ inline float bhi(uint u) { return __uint_as_float(u & 0xffff0000u); }
__device__ inline ushort f2bu(float x) {
    __hip_bfloat16 h = __float2bfloat16(x);
    return *reinterpret_cast<ushort*>(&h);
}
__device__ inline uint fpack2(float x, float y) {
    return (uint)f2bu(x) | ((uint)f2bu(y) << 16);
}

// ================= bucketed CSR build =================
// Buckets of 512 nodes (NB = ceil(n/512) <= 256). NBLK = 256 scatter blocks.
// pairs[e] = (src << 9) | (dst & 511), grouped by bucket.

__global__ __launch_bounds__(256) void hist_k(const int* __restrict__ ei,
                                              uint* __restrict__ hist, int E, int n) {
    __shared__ uint h[256];
    int t = threadIdx.x, blk = blockIdx.x;
    int nb = (n + 511) >> 9;
    h[t] = 0;
    __syncthreads();
    int chunk = (E + 255) / 256;
    int e0 = blk * chunk, e1 = min(E, e0 + chunk);
    for (int e = e0 + t; e < e1; e += 256)
        atomicAdd(&h[((uint)ei[(size_t)E + e]) >> 9], 1u);
    __syncthreads();
    if (t < nb) hist[(size_t)t * 256 + blk] = h[t];
}

__global__ __launch_bounds__(256) void scanA_k(const uint* __restrict__ hist,
                                               uint* __restrict__ histex,
                                               uint* __restrict__ btot) {
    __shared__ uint s[256];
    int t = threadIdx.x, b = blockIdx.x;
    uint v = hist[(size_t)b * 256 + t];
    s[t] = v;
    __syncthreads();
    for (int off = 1; off < 256; off <<= 1) {
        uint u = (t >= off) ? s[t - off] : 0;
        __syncthreads();
        s[t] += u;
        __syncthreads();
    }
    histex[(size_t)b * 256 + t] = s[t] - v;   // exclusive within bucket
    if (t == 255) btot[b] = s[255];
}

__global__ __launch_bounds__(256) void scanB_k(const uint* __restrict__ btot,
                                               uint* __restrict__ bbase,
                                               int* __restrict__ rp, int n, int E) {
    __shared__ uint s[256];
    int t = threadIdx.x;
    int nb = (n + 511) >> 9;
    uint v = (t < nb) ? btot[t] : 0;
    s[t] = v;
    __syncthreads();
    for (int off = 1; off < 256; off <<= 1) {
        uint u = (t >= off) ? s[t - off] : 0;
        __syncthreads();
        s[t] += u;
        __syncthreads();
    }
    if (t < nb) bbase[t] = s[t] - v;
    if (t == nb - 1) bbase[nb] = s[t];
    if (t == 0) rp[n] = E;
}

__global__ __launch_bounds__(256) void scat_k(const int* __restrict__ ei,
                                              const uint* __restrict__ bbase,
                                              const uint* __restrict__ histex,
                                              uint* __restrict__ pairs, int E, int n) {
    __shared__ uint cur[256];
    int t = threadIdx.x, blk = blockIdx.x;
    int nb = (n + 511) >> 9;
    if (t < nb) cur[t] = bbase[t] + histex[(size_t)t * 256 + blk];
    __syncthreads();
    int chunk = (E + 255) / 256;
    int e0 = blk * chunk, e1 = min(E, e0 + chunk);
    for (int e = e0 + t; e < e1; e += 256) {
        uint src = (uint)ei[e];
        uint dst = (uint)ei[(size_t)E + e];
        uint p = atomicAdd(&cur[dst >> 9], 1u);
        pairs[p] = (src << 9) | (dst & 511u);
    }
}

__global__ __launch_bounds__(256) void build_k(const uint* __restrict__ pairs,
                                               const uint* __restrict__ bbase,
                                               int* __restrict__ rp,
                                               float* __restrict__ dinv,
                                               int* __restrict__ eb, int n) {
    __shared__ uint lcnt[512];
    __shared__ uint lsc[256];
    int t = threadIdx.x, b = blockIdx.x;
    uint e0 = bbase[b], e1 = bbase[b + 1];
    lcnt[t] = 0;
    lcnt[t + 256] = 0;
    __syncthreads();
    for (uint e = e0 + t; e < e1; e += 256)
        atomicAdd(&lcnt[pairs[e] & 511u], 1u);
    __syncthreads();
    uint c0 = lcnt[2 * t], c1 = lcnt[2 * t + 1];
    uint sm = c0 + c1;
    lsc[t] = sm;
    __syncthreads();
    for (int off = 1; off < 256; off <<= 1) {
        uint u = (t >= off) ? lsc[t - off] : 0;
        __syncthreads();
        lsc[t] += u;
        __syncthreads();
    }
    uint ex = lsc[t] - sm;
    int node0 = (b << 9) + 2 * t;
    if (node0 < n) {
        rp[node0] = (int)(e0 + ex);
        dinv[node0] = rsqrtf((float)(c0 + 1));
    }
    if (node0 + 1 < n) {
        rp[node0 + 1] = (int)(e0 + ex + c0);
        dinv[node0 + 1] = rsqrtf((float)(c1 + 1));
    }
    lcnt[2 * t] = e0 + ex;
    lcnt[2 * t + 1] = e0 + ex + c0;
    __syncthreads();
    for (uint e = e0 + t; e < e1; e += 256) {
        uint p = pairs[e];
        uint pos = atomicAdd(&lcnt[p & 511u], 1u);
        eb[pos] = (int)(p >> 9);
    }
}

// ================= MFMA bf16 GEMM =================
// out[r][c] = bf16( (sum_k X[r][k]*W[k][c]) * dinv[r] ), 128 rows/block, K=128.
// A and Wt staged bf16 in LDS, XOR-swizzled ((row&7)<<4) for conflict-free b128 reads.

template <int OUTC, bool INB>
__global__ __launch_bounds__(256) void mgemm_k(const void* __restrict__ Xv,
                                               const float* __restrict__ W,
                                               const float* __restrict__ dinv,
                                               uint* __restrict__ outb, int n) {
    constexpr int WOFF = 32768;
    constexpr int C4 = OUTC / 4;
    constexpr int NC = OUTC / 16;
    constexpr int LDSB = (32768 + OUTC * 256) > (128 * OUTC * 4)
                             ? (32768 + OUTC * 256) : (128 * OUTC * 4);
    __shared__ uint4 ldsv[LDSB / 16];
    char* lds = (char*)ldsv;

    int t = threadIdx.x;
    int r0b = blockIdx.x * 128;

    // stage Wt: bf16 [col][k], swizzled
    for (int i = t; i < 128 * C4; i += 256) {
        int k = i / C4, c0 = (i % C4) * 4;
        float4 w = ((const float4*)W)[i];
        const float* wf = (const float*)&w;
#pragma unroll
        for (int j = 0; j < 4; ++j) {
            int c = c0 + j;
            *(ushort*)(lds + WOFF + c * 256 + ((k * 2) ^ ((c & 7) << 4))) = f2bu(wf[j]);
        }
    }
    // stage A: bf16 [row][k], swizzled.  Row = 128 bf16 = 256 B.
    if constexpr (!INB) {
        for (int i = t; i < 128 * 32; i += 256) {
            int r = i >> 5, kq = i & 31;
            uint2 p = make_uint2(0u, 0u);
            if (r0b + r < n) {
                float4 v = ((const float4*)Xv)[(size_t)(r0b + r) * 32 + kq];
                p = make_uint2(fpack2(v.x, v.y), fpack2(v.z, v.w));
            }
            *(uint2*)(lds + r * 256 + ((kq * 8) ^ ((r & 7) << 4))) = p;
        }
    } else {
        // bf16 input: 128 ch = 256 B = 16 uint4 per row  (round-3 bug: was 8)
        for (int i = t; i < 128 * 16; i += 256) {
            int r = i >> 4, kq = i & 15;
            uint4 p = make_uint4(0u, 0u, 0u, 0u);
            if (r0b + r < n) p = ((const uint4*)Xv)[(size_t)(r0b + r) * 16 + kq];
            *(uint4*)(lds + r * 256 + ((kq * 16) ^ ((r & 7) << 4))) = p;
        }
    }
    __syncthreads();

    int wv = t >> 6, lane = t & 63;
    int l15 = lane & 15, lg = lane >> 4;
    int wr0 = wv * 32;
    int swz = (l15 & 7) << 4;

    f32x4 acc[2][NC];
#pragma unroll
    for (int r = 0; r < 2; ++r)
#pragma unroll
        for (int cj = 0; cj < NC; ++cj) acc[r][cj] = (f32x4){0.f, 0.f, 0.f, 0.f};

#pragma unroll
    for (int kk = 0; kk < 4; ++kk) {
        int koff = kk * 64 + lg * 16;
        bf16x8 a0 = *(bf16x8*)(lds + (wr0 + l15) * 256 + (koff ^ swz));
        bf16x8 a1 = *(bf16x8*)(lds + (wr0 + 16 + l15) * 256 + (koff ^ swz));
#pragma unroll
        for (int cj = 0; cj < NC; ++cj) {
            int c = cj * 16 + l15;
            bf16x8 bv = *(bf16x8*)(lds + WOFF + c * 256 + (koff ^ swz));
            acc[0][cj] = __builtin_amdgcn_mfma_f32_16x16x32_bf16(a0, bv, acc[0][cj], 0, 0, 0);
            acc[1][cj] = __builtin_amdgcn_mfma_f32_16x16x32_bf16(a1, bv, acc[1][cj], 0, 0, 0);
        }
    }
    __syncthreads();

    // D -> LDS f32 [128][OUTC]  (C/D layout: col = lane&15, row = (lane>>4)*4 + reg)
#pragma unroll
    for (int r = 0; r < 2; ++r)
#pragma unroll
        for (int cj = 0; cj < NC; ++cj) {
            int row = wr0 + r * 16 + lg * 4;
            int col = cj * 16 + l15;
#pragma unroll
            for (int j = 0; j < 4; ++j)
                *(float*)(lds + ((size_t)(row + j) * OUTC + col) * 4) = acc[r][cj][j];
        }
    __syncthreads();

    for (int i = t; i < 128 * C4; i += 256) {
        int r = i / C4, c4 = (i % C4) * 4;
        if (r0b + r < n) {
            float di = dinv[r0b + r];
            float4 d = *(float4*)(lds + (size_t)i * 16);
            uint2 p = make_uint2(fpack2(d.x * di, d.y * di), fpack2(d.z * di, d.w * di));
            *(uint2*)&outb[(size_t)(r0b + r) * (OUTC / 2) + (c4 >> 1)] = p;
        }
    }
}

// ================= Aggregation =================

__global__ __launch_bounds__(256) void agg128_k(const uint* __restrict__ hs,
                                                const int* __restrict__ rp,
                                                const int* __restrict__ eb,
                                                const float* __restrict__ dinv,
                                                const float* __restrict__ bias,
                                                uint* __restrict__ outb, int n) {
    int wid = (blockIdx.x * 256 + threadIdx.x) >> 6;
    int lane = threadIdx.x & 63;
    if (wid >= n) return;
    int e0 = rp[wid], e1 = rp[wid + 1];
    float di = dinv[wid];
    const uint* base = hs + lane;

    uint self = base[(size_t)wid << 6];
    float ax = blo(self), ay = bhi(self);

    int e = e0;
    for (; e + 8 <= e1; e += 8) {
        int s0 = eb[e + 0], s1 = eb[e + 1], s2 = eb[e + 2], s3 = eb[e + 3];
        int s4 = eb[e + 4], s5 = eb[e + 5], s6 = eb[e + 6], s7 = eb[e + 7];
        uint v0 = base[(size_t)s0 << 6];
        uint v1 = base[(size_t)s1 << 6];
        uint v2 = base[(size_t)s2 << 6];
        uint v3 = base[(size_t)s3 << 6];
        uint v4 = base[(size_t)s4 << 6];
        uint v5 = base[(size_t)s5 << 6];
        uint v6 = base[(size_t)s6 << 6];
        uint v7 = base[(size_t)s7 << 6];
        ax += ((blo(v0) + blo(v1)) + (blo(v2) + blo(v3))) +
              ((blo(v4) + blo(v5)) + (blo(v6) + blo(v7)));
        ay += ((bhi(v0) + bhi(v1)) + (bhi(v2) + bhi(v3))) +
              ((bhi(v4) + bhi(v5)) + (bhi(v6) + bhi(v7)));
    }
    for (; e < e1; ++e) {
        uint v = base[(size_t)eb[e] << 6];
        ax += blo(v);
        ay += bhi(v);
    }

    float ox = fmaxf(ax * di + bias[lane * 2], 0.f);
    float oy = fmaxf(ay * di + bias[lane * 2 + 1], 0.f);
    outb[((size_t)wid << 6) + lane] = fpack2(ox, oy);
}

__global__ __launch_bounds__(256) void agg64_k(const uint* __restrict__ hs,
                                               const int* __restrict__ rp,
                                               const int* __restrict__ eb,
                                               const float* __restrict__ dinv,
                                               const float* __restrict__ bias,
                                               float* __restrict__ out, int n) {
    int gw = (blockIdx.x * 256 + threadIdx.x) >> 6;
    int lane = threadIdx.x & 63;
    int node = gw * 2 + (lane >> 5);
    int cl = lane & 31;
    if (node >= n) return;
    int e0 = rp[node], e1 = rp[node + 1];
    float di = dinv[node];
    const uint* base = hs + cl;

    uint self = base[(size_t)node << 5];
    float ax = blo(self), ay = bhi(self);

    int e = e0;
    for (; e + 8 <= e1; e += 8) {
        int s0 = eb[e + 0], s1 = eb[e + 1], s2 = eb[e + 2], s3 = eb[e + 3];
        int s4 = eb[e + 4], s5 = eb[e + 5], s6 = eb[e + 6], s7 = eb[e + 7];
        uint v0 = base[(size_t)s0 << 5];
        uint v1 = base[(size_t)s1 << 5];
        uint v2 = base[(size_t)s2 << 5];
        uint v3 = base[(size_t)s3 << 5];
        uint v4 = base[(size_t)s4 << 5];
        uint v5 = base[(size_t)s5 << 5];
        uint v6 = base[(size_t)s6 << 5];
        uint v7 = base[(size_t)s7 << 5];
        ax += ((blo(v0) + blo(v1)) + (blo(v2) + blo(v3))) +
              ((blo(v4) + blo(v5)) + (blo(v6) + blo(v7)));
        ay += ((bhi(v0) + bhi(v1)) + (bhi(v2) + bhi(v3))) +
              ((bhi(v4) + bhi(v5)) + (bhi(v6) + bhi(v7)));
    }
    for (; e < e1; ++e) {
        uint v = base[(size_t)eb[e] << 5];
        ax += blo(v);
        ay += bhi(v);
    }

    float ox = ax * di + bias[cl * 2];
    float oy = ay * di + bias[cl * 2 + 1];
    *(float2*)&out[((size_t)node << 6) + cl * 2] = make_float2(ox, oy);
}

// ================= launch =================

extern "C" void kernel_launch(void* const* d_in, const int* in_sizes, int n_in,
                              void* d_out, int out_size, void* d_ws, size_t ws_size,
                              hipStream_t stream) {
    const float* x  = (const float*)d_in[0];
    const int*   ei = (const int*)d_in[1];
    const float* W1 = (const float*)d_in[2];
    const float* b1 = (const float*)d_in[3];
    const float* W2 = (const float*)d_in[4];
    const float* b2 = (const float*)d_in[5];
    float* out = (float*)d_out;

    int n = in_sizes[0] / 128;
    int E = in_sizes[1] / 2;
    int nb = (n + 511) >> 9;   // buckets of 512 nodes

    char* ws = (char*)d_ws;
    size_t o = 0;
    auto alloc = [&](size_t bytes) {
        size_t r = o;
        o = (o + bytes + 255) & ~(size_t)255;
        return r;
    };
    uint*  hist   = (uint*)(ws + alloc((size_t)256 * 256 * 4));
    uint*  histex = (uint*)(ws + alloc((size_t)256 * 256 * 4));
    uint*  btot   = (uint*)(ws + alloc(256 * 4));
    uint*  bbase  = (uint*)(ws + alloc(257 * 4));
    int*   rp     = (int*)(ws + alloc((size_t)(n + 1) * 4));
    float* dinv   = (float*)(ws + alloc((size_t)n * 4));
    uint*  pairs  = (uint*)(ws + alloc((size_t)E * 4));
    int*   eb     = (int*)(ws + alloc((size_t)E * 4));
    uint*  h1s    = (uint*)(ws + alloc((size_t)n * 64 * 4));  // bf16 x2, 128 ch
    uint*  a1     = (uint*)(ws + alloc((size_t)n * 64 * 4));  // bf16 x2, 128 ch
    uint*  h2s    = (uint*)(ws + alloc((size_t)n * 32 * 4));  // bf16 x2, 64 ch

    int gB = (n + 127) / 128;
    int gW1 = (int)(((size_t)n * 64 + 255) / 256);
    int nw2 = (n + 1) / 2;
    int gW2 = (int)(((size_t)nw2 * 64 + 255) / 256);

    // CSR build
    hist_k<<<256, 256, 0, stream>>>(ei, hist, E, n);
    scanA_k<<<nb, 256, 0, stream>>>(hist, histex, btot);
    scanB_k<<<1, 256, 0, stream>>>(btot, bbase, rp, n, E);
    scat_k<<<256, 256, 0, stream>>>(ei, bbase, histex, pairs, E, n);
    build_k<<<nb, 256, 0, stream>>>(pairs, bbase, rp, dinv, eb, n);

    // layer 1: h1s = bf16((x@W1) * dinv) ; a1 = bf16(relu(agg(h1s)*dinv + b1))
    mgemm_k<128, false><<<gB, 256, 0, stream>>>(x, W1, dinv, h1s, n);
    agg128_k<<<gW1, 256, 0, stream>>>(h1s, rp, eb, dinv, b1, a1, n);
    // layer 2: h2s = bf16((a1@W2) * dinv) ; out = agg(h2s)*dinv + b2 (f32)
    mgemm_k<64, true><<<gB, 256, 0, stream>>>(a1, W2, dinv, h2s, n);
    agg64_k<<<gW2, 256, 0, stream>>>(h2s, rp, eb, dinv, b2, out, n);
}